// Round 15
// baseline (5190.990 us; speedup 1.0000x reference)
//
#include <hip/hip_runtime.h>
#include <stdint.h>

#define Hdim 512
#define Bsz 64
#define Tlen 1024
#define RING 8
#define GR (RING * 16 * Hdim)  // ring shorts per (layer,group)
#define FSTR 16                // flag stride in words (one flag per 64-B line)
#define LROW 520               // shorts per LDS row: 1040 B stride, 16-B aligned

typedef __attribute__((ext_vector_type(8))) short short8;
typedef __attribute__((ext_vector_type(4))) int i32x4;
typedef __attribute__((ext_vector_type(4))) float f32x4;
typedef unsigned long long u64;

__device__ __forceinline__ short f2bf(float f) {
  uint32_t u = __float_as_uint(f);
  u += 0x7fffu + ((u >> 16) & 1u);   // RNE
  return (short)(u >> 16);
}

__device__ __forceinline__ f32x4 mfma16(short8 a, short8 b, f32x4 c) {
  return __builtin_amdgcn_mfma_f32_16x16x32_bf16(a, b, c, 0, 0, 0);
}

// Poll: lane watches *pp until >= tgt (no backoff; detect ASAP).
__device__ __forceinline__ void wait_multi(const uint32_t* pp, uint32_t tgt) {
  uint32_t it = 0;
  for (;;) {
    uint32_t v = __hip_atomic_load(pp, __ATOMIC_RELAXED, __HIP_MEMORY_SCOPE_AGENT);
    if (__all((int)(v >= tgt))) break;
    if (++it > (1u << 22)) break;  // failsafe against hang
  }
}

// Coherent coalesced staging: 8 x dwordx4 sc0 sc1, ONE asm block.
// SAFETY: outputs EARLY-CLOBBER ("=&v") so no output VGPR aliases an address
// register (R12 lesson: async data-return corrupts aliased addr); s_waitcnt
// INSIDE the block (R3 lesson). NO offset immediates (R13/R14 lesson: the
// assembler rejects `off sc0 sc1 offset:N` ordering; R12 proved the no-offset
// form assembles) -> 8 separate base addresses.
__device__ __forceinline__ void stage_both(const short* __restrict__ srcA,
                                           const short* __restrict__ srcB,
                                           short* __restrict__ ldsA,
                                           short* __restrict__ ldsB,
                                           int wave, int lane) {
  const int r0 = wave * 4;
  const short* pa0 = srcA + (r0 + 0) * 512 + lane * 8;
  const short* pa1 = srcA + (r0 + 1) * 512 + lane * 8;
  const short* pa2 = srcA + (r0 + 2) * 512 + lane * 8;
  const short* pa3 = srcA + (r0 + 3) * 512 + lane * 8;
  const short* pb0 = srcB + (r0 + 0) * 512 + lane * 8;
  const short* pb1 = srcB + (r0 + 1) * 512 + lane * 8;
  const short* pb2 = srcB + (r0 + 2) * 512 + lane * 8;
  const short* pb3 = srcB + (r0 + 3) * 512 + lane * 8;
  i32x4 t0, t1, t2, t3, t4, t5, t6, t7;
  asm volatile(
      "global_load_dwordx4 %0, %8, off sc0 sc1\n\t"
      "global_load_dwordx4 %1, %9, off sc0 sc1\n\t"
      "global_load_dwordx4 %2, %10, off sc0 sc1\n\t"
      "global_load_dwordx4 %3, %11, off sc0 sc1\n\t"
      "global_load_dwordx4 %4, %12, off sc0 sc1\n\t"
      "global_load_dwordx4 %5, %13, off sc0 sc1\n\t"
      "global_load_dwordx4 %6, %14, off sc0 sc1\n\t"
      "global_load_dwordx4 %7, %15, off sc0 sc1\n\t"
      "s_waitcnt vmcnt(0)"
      : "=&v"(t0), "=&v"(t1), "=&v"(t2), "=&v"(t3),
        "=&v"(t4), "=&v"(t5), "=&v"(t6), "=&v"(t7)
      : "v"(pa0), "v"(pa1), "v"(pa2), "v"(pa3),
        "v"(pb0), "v"(pb1), "v"(pb2), "v"(pb3)
      : "memory");
  *(i32x4*)(ldsA + (r0 + 0) * LROW + lane * 8) = t0;
  *(i32x4*)(ldsA + (r0 + 1) * LROW + lane * 8) = t1;
  *(i32x4*)(ldsA + (r0 + 2) * LROW + lane * 8) = t2;
  *(i32x4*)(ldsA + (r0 + 3) * LROW + lane * 8) = t3;
  *(i32x4*)(ldsB + (r0 + 0) * LROW + lane * 8) = t4;
  *(i32x4*)(ldsB + (r0 + 1) * LROW + lane * 8) = t5;
  *(i32x4*)(ldsB + (r0 + 2) * LROW + lane * 8) = t6;
  *(i32x4*)(ldsB + (r0 + 3) * LROW + lane * 8) = t7;
}

// MFMA A-fragment from staged LDS: single b128 (16-B aligned by LROW=520).
__device__ __forceinline__ short8 frag_read(const short* __restrict__ lds,
                                            int lane, int ks) {
  return *(const short8*)(lds + (lane & 15) * LROW + (lane >> 4) * 8 + ks * 32);
}

__global__ void out_init(float* out, const float* bout) {
  int i = blockIdx.x * 256 + threadIdx.x;
  if (i < Bsz * Tlen) out[i] = bout[0];
}

// ---- weight pack: unchanged from R6-R14 (verified correct) ----
__global__ void pack_kernel(const float* __restrict__ Whh0,
                            const float* __restrict__ Wih1, const float* __restrict__ Whh1,
                            const float* __restrict__ Wih2, const float* __restrict__ Whh2,
                            short* __restrict__ Bpack) {
  int ch = blockIdx.x * 256 + threadIdx.x;
  const int L0C = 64 * 16 * 2 * 64;
  const int L12C = 64 * 32 * 2 * 64;
  if (ch >= L0C + 2 * L12C) return;
  int layer, rel, KS;
  const float* Wih;
  const float* Whh;
  if (ch < L0C) { layer = 0; rel = ch; KS = 16; Wih = nullptr; Whh = Whh0; }
  else if (ch < L0C + L12C) { layer = 1; rel = ch - L0C; KS = 32; Wih = Wih1; Whh = Whh1; }
  else { layer = 2; rel = ch - L0C - L12C; KS = 32; Wih = Wih2; Whh = Whh2; }
  int lane = rel & 63;
  int nt = (rel >> 6) & 1;
  int rest = rel >> 7;          // (d*4+w)*KS + ks
  int ks = rest % KS;
  int dw = rest / KS;
  int w = dw & 3;
  int d = dw >> 2;
  int col = nt * 16 + (lane & 15);
  int row = (col >> 3) * Hdim + d * 32 + w * 8 + (col & 7);
  int kbase = ks * 32 + (lane >> 4) * 8;
  short8 v;
#pragma unroll
  for (int e = 0; e < 8; ++e) {
    int k = kbase + e;
    float wt;
    if (layer == 0) wt = Whh[row * Hdim + k];
    else wt = (k < Hdim) ? Wih[row * Hdim + k] : Whh[row * Hdim + (k - Hdim)];
    v[e] = f2bf(wt);
  }
  ((short8*)Bpack)[ch] = v;
}

__global__ __launch_bounds__(256, 1)
void lstm_persist(const float* __restrict__ x,
                  const float* __restrict__ Wih0v,
                  const float* __restrict__ bih0, const float* __restrict__ bhh0,
                  const float* __restrict__ bih1, const float* __restrict__ bhh1,
                  const float* __restrict__ bih2, const float* __restrict__ bhh2,
                  const float* __restrict__ Wout,
                  const short* __restrict__ Bpack,
                  short* __restrict__ rings,
                  uint32_t* __restrict__ flags,
                  float* __restrict__ out) {
  const int blk = blockIdx.x;
  const int layer = blk >> 6;          // 0..2
  const int g = (blk >> 4) & 3;        // batch group (16 rows)
  const int d = blk & 15;              // dim-block (32 h-dims)
  const int tid = threadIdx.x;
  const int lane = tid & 63;
  const int wave = tid >> 6;           // 0..3 = N-slice; role split at publish/poll

  __shared__ short ldsA[16 * LROW];    // staged prev-layer h
  __shared__ short ldsB[16 * LROW];    // staged own-layer h
  __shared__ short hbuf[16][32];       // [group-row][dim within block]
  __shared__ float pbuf[4][16];        // out-head partials [wave][group-row]

  // ---- persistent B fragments: plain loads + keepalive pin (R4-R11-proven) ----
  short8 bw[32][2];
  {
    const short8* bp = (const short8*)Bpack;
    if (layer == 0) {
#pragma unroll
      for (int ks = 0; ks < 16; ++ks) {
        bw[ks][0] = bp[((((d * 4 + wave) * 16 + ks) * 2 + 0) * 64) + lane];
        bw[ks][1] = bp[((((d * 4 + wave) * 16 + ks) * 2 + 1) * 64) + lane];
        asm volatile("" : "+v"(bw[ks][0]), "+v"(bw[ks][1]));
      }
    } else {
      const int base = (layer == 1) ? 131072 : 393216;
#pragma unroll
      for (int ks = 0; ks < 32; ++ks) {
        bw[ks][0] = bp[base + (((d * 4 + wave) * 32 + ks) * 2 + 0) * 64 + lane];
        bw[ks][1] = bp[base + (((d * 4 + wave) * 32 + ks) * 2 + 1) * 64 + lane];
        asm volatile("" : "+v"(bw[ks][0]), "+v"(bw[ks][1]));
      }
    }
  }

  const float* bih = (layer == 0) ? bih0 : (layer == 1 ? bih1 : bih2);
  const float* bhh = (layer == 0) ? bhh0 : (layer == 1 ? bhh1 : bhh2);
  const int dimb = d * 32 + wave * 8 + (lane & 7);
  const int row0 = (((lane & 15) >> 3)) * Hdim + dimb;       // gates i/f
  const int row1 = (((lane & 15) >> 3) + 2) * Hdim + dimb;   // gates g/o
  const float bias0 = bih[row0] + bhh[row0];
  const float bias1 = bih[row1] + bhh[row1];
  float xw0 = 0.f, xw1 = 0.f, woutd = 0.f;
  if (layer == 0) { xw0 = Wih0v[row0]; xw1 = Wih0v[row1]; }
  if (layer == 2) woutd = Wout[dimb];

  uint32_t* flagsO = flags + ((layer * 4 + g) * 16) * FSTR;
  const uint32_t* flagsP = flags + (((layer - 1) * 4 + g) * 16) * FSTR;  // guarded layer>0
  const uint32_t* flagsN = flags + (((layer + 1) * 4 + g) * 16) * FSTR;  // guarded layer<2
  short* ringLG = rings + (layer * 4 + g) * GR;
  const short* ringPG = rings + ((layer - 1) * 4 + g) * GR;

  // wave-1 poll lanes: 0-15 own (tgt t), 16-31 prev (tgt t+1, layer>0),
  // 32-47 next-layer backpressure (tgt t+1-RING, layer<2), rest trivial.
  const uint32_t* pptr;
  int pmode;  // 0=own, 1=prev, 2=bp, 3=trivial
  if (lane < 16) { pptr = flagsO + lane * FSTR; pmode = 0; }
  else if (lane < 32 && layer > 0) { pptr = flagsP + (lane - 16) * FSTR; pmode = 1; }
  else if (lane >= 32 && lane < 48 && layer < 2) { pptr = flagsN + (lane - 32) * FSTR; pmode = 2; }
  else { pptr = flagsO; pmode = 3; }

  const int bR = 4 * (lane >> 4);      // group-row base for acc rows

  float c[4] = {0.f, 0.f, 0.f, 0.f};

  for (int t = 0; t < Tlen; ++t) {
    // ---- poll (wave 1) — overlaps wave 0's publish of step t-1 ----
    if (wave == 1) {
      uint32_t tgt;
      if (pmode == 0) tgt = (uint32_t)t;
      else if (pmode == 1) tgt = (uint32_t)(t + 1);
      else if (pmode == 2) tgt = (t + 1 >= RING) ? (uint32_t)(t + 1 - RING) : 0u;
      else tgt = 0u;
      wait_multi(pptr, tgt);
    }
    __syncthreads();  // bar1: poll passed AND wave 0's prior publish ack'd

    // ---- coalesced staging burst (both slots; dummies when absent) ----
    {
      const short* srcA = (layer > 0) ? ringPG + (t & (RING - 1)) * (16 * Hdim) : ringLG;
      const short* srcB = (t > 0) ? ringLG + ((t - 1) & (RING - 1)) * (16 * Hdim) : srcA;
      stage_both(srcA, srcB, ldsA, ldsB, wave, lane);
    }
    __syncthreads();  // bar2: staging complete

    // ---- MFMA ----
    f32x4 acc0 = {bias0, bias0, bias0, bias0};
    f32x4 acc1 = {bias1, bias1, bias1, bias1};
    if (layer > 0) {
#pragma unroll
      for (int ks = 0; ks < 16; ++ks) {
        short8 a = frag_read(ldsA, lane, ks);
        acc0 = mfma16(a, bw[ks][0], acc0);
        acc1 = mfma16(a, bw[ks][1], acc1);
      }
    } else if (t > 0) {
#pragma unroll
      for (int r = 0; r < 4; ++r) {
        float xv = x[(g * 16 + bR + r) * Tlen + (t - 1)];  // DELAY=1
        acc0[r] += xw0 * xv;
        acc1[r] += xw1 * xv;
      }
    }
    if (t > 0) {
      if (layer == 0) {
#pragma unroll
        for (int ks = 0; ks < 16; ++ks) {
          short8 a = frag_read(ldsB, lane, ks);
          acc0 = mfma16(a, bw[ks][0], acc0);
          acc1 = mfma16(a, bw[ks][1], acc1);
        }
      } else {
#pragma unroll
        for (int ks = 0; ks < 16; ++ks) {
          short8 a = frag_read(ldsB, lane, ks);
          acc0 = mfma16(a, bw[16 + ks][0], acc0);
          acc1 = mfma16(a, bw[16 + ks][1], acc1);
        }
      }
    }

    // ---- activations / state update ----
    float parts[4];
#pragma unroll
    for (int r = 0; r < 4; ++r) {
      float a0 = acc0[r], a1 = acc1[r];
      float p0 = __shfl_xor(a0, 8);
      float p1 = __shfl_xor(a1, 8);
      float iv = 1.f / (1.f + __expf(-a0));
      float fv = 1.f / (1.f + __expf(-p0));
      float gv = tanhf(a1);
      float ov = 1.f / (1.f + __expf(-p1));
      c[r] = fv * c[r] + iv * gv;
      float hv = ov * tanhf(c[r]);
      if ((lane & 8) == 0) hbuf[bR + r][wave * 8 + (lane & 7)] = f2bf(hv);
      parts[r] = hv * woutd;
    }
    if (layer == 2) {
#pragma unroll
      for (int r = 0; r < 4; ++r) {
        parts[r] += __shfl_xor(parts[r], 1);
        parts[r] += __shfl_xor(parts[r], 2);
        parts[r] += __shfl_xor(parts[r], 4);
        if ((lane & 15) == 0) pbuf[wave][bR + r] = parts[r];
      }
    }

    __syncthreads();  // bar3: hbuf (+ pbuf) complete

    // ---- publish (wave 0 only): 1 dwordx4 sc0 sc1 per lane + in-asm ack ----
    if (wave == 0) {
      short* hout = ringLG + (t & (RING - 1)) * (16 * Hdim);
      int row = lane >> 2, q = lane & 3;
      i32x4 v = *(const i32x4*)&hbuf[row][q * 8];
      short* dst = hout + row * Hdim + d * 32 + q * 8;
      asm volatile("global_store_dwordx4 %0, %1, off sc0 sc1\n\t"
                   "s_waitcnt vmcnt(0)"
                   :: "v"(dst), "v"(v) : "memory");
      if (lane == 0)
        __hip_atomic_store(flagsO + d * FSTR, (uint32_t)(t + 1), __ATOMIC_RELAXED,
                           __HIP_MEMORY_SCOPE_AGENT);
    }
    // out-head fully off critical path (wave 2; pbuf stable until next act)
    if (layer == 2 && wave == 2 && lane < 16) {
      float s = pbuf[0][lane] + pbuf[1][lane] + pbuf[2][lane] + pbuf[3][lane];
      atomicAdd(out + (g * 16 + lane) * Tlen + t, s);
    }
  }
}

extern "C" void kernel_launch(void* const* d_in, const int* in_sizes, int n_in,
                              void* d_out, int out_size, void* d_ws, size_t ws_size,
                              hipStream_t stream) {
  const float* x    = (const float*)d_in[0];
  const float* Wih0 = (const float*)d_in[1];
  const float* Whh0 = (const float*)d_in[2];
  const float* bih0 = (const float*)d_in[3];
  const float* bhh0 = (const float*)d_in[4];
  const float* Wih1 = (const float*)d_in[5];
  const float* Whh1 = (const float*)d_in[6];
  const float* bih1 = (const float*)d_in[7];
  const float* bhh1 = (const float*)d_in[8];
  const float* Wih2 = (const float*)d_in[9];
  const float* Whh2 = (const float*)d_in[10];
  const float* bih2 = (const float*)d_in[11];
  const float* bhh2 = (const float*)d_in[12];
  const float* Wout = (const float*)d_in[13];
  const float* bout = (const float*)d_in[14];

  char* ws = (char*)d_ws;
  short* Bpack    = (short*)ws;                          // 10,485,760 B
  short* rings    = (short*)(ws + 10485760);             // 1,572,864 B
  uint32_t* flags = (uint32_t*)(ws + 12058624);          // 12,288 B (total ~12.07 MB, proven)
  float* out      = (float*)d_out;

  (void)hipMemsetAsync(flags, 0, 12 * 16 * FSTR * sizeof(uint32_t), stream);
  out_init<<<(Bsz * Tlen + 255) / 256, 256, 0, stream>>>(out, bout);
  pack_kernel<<<2560, 256, 0, stream>>>(Whh0, Wih1, Whh1, Wih2, Whh2, Bpack);
  lstm_persist<<<192, 256, 0, stream>>>(x, Wih0, bih0, bhh0, bih1, bhh1, bih2, bhh2,
                                        Wout, Bpack, rings, flags, out);
}

// Round 18
// 5140.746 us; speedup vs baseline: 1.0098x; 1.0098x over previous
//
#include <hip/hip_runtime.h>
#include <stdint.h>

#define Hdim 512
#define Bsz 64
#define Tlen 1024
#define RING 8
#define GR (RING * 16 * Hdim)  // ring shorts per (layer,group)
#define FSTR 16                // flag stride in words (one flag per 64-B line)
#define LROW 520               // shorts per LDS row: 1040 B stride, 16-B aligned

typedef __attribute__((ext_vector_type(8))) short short8;
typedef __attribute__((ext_vector_type(4))) int i32x4;
typedef __attribute__((ext_vector_type(4))) float f32x4;
typedef unsigned long long u64;

__device__ __forceinline__ short f2bf(float f) {
  uint32_t u = __float_as_uint(f);
  u += 0x7fffu + ((u >> 16) & 1u);   // RNE
  return (short)(u >> 16);
}

__device__ __forceinline__ f32x4 mfma16(short8 a, short8 b, f32x4 c) {
  return __builtin_amdgcn_mfma_f32_16x16x32_bf16(a, b, c, 0, 0, 0);
}

// Poll: lane watches *pp until >= tgt (no backoff; detect ASAP).
__device__ __forceinline__ void wait_multi(const uint32_t* pp, uint32_t tgt) {
  uint32_t it = 0;
  for (;;) {
    uint32_t v = __hip_atomic_load(pp, __ATOMIC_RELAXED, __HIP_MEMORY_SCOPE_AGENT);
    if (__all((int)(v >= tgt))) break;
    if (++it > (1u << 22)) break;  // failsafe against hang
  }
}

// Coherent coalesced staging: 8 x dwordx4 sc0 sc1, ONE asm block.
// SAFETY: outputs EARLY-CLOBBER ("=&v") so no output VGPR aliases an address
// register (R12 lesson: async data-return corrupts aliased addr); s_waitcnt
// INSIDE the block (R3 lesson). NO offset immediates (R13/R14 lesson) ->
// 8 separate base addresses.
__device__ __forceinline__ void stage_both(const short* __restrict__ srcA,
                                           const short* __restrict__ srcB,
                                           short* __restrict__ ldsA,
                                           short* __restrict__ ldsB,
                                           int wave, int lane) {
  const int r0 = wave * 4;
  const short* pa0 = srcA + (r0 + 0) * 512 + lane * 8;
  const short* pa1 = srcA + (r0 + 1) * 512 + lane * 8;
  const short* pa2 = srcA + (r0 + 2) * 512 + lane * 8;
  const short* pa3 = srcA + (r0 + 3) * 512 + lane * 8;
  const short* pb0 = srcB + (r0 + 0) * 512 + lane * 8;
  const short* pb1 = srcB + (r0 + 1) * 512 + lane * 8;
  const short* pb2 = srcB + (r0 + 2) * 512 + lane * 8;
  const short* pb3 = srcB + (r0 + 3) * 512 + lane * 8;
  i32x4 t0, t1, t2, t3, t4, t5, t6, t7;
  asm volatile(
      "global_load_dwordx4 %0, %8, off sc0 sc1\n\t"
      "global_load_dwordx4 %1, %9, off sc0 sc1\n\t"
      "global_load_dwordx4 %2, %10, off sc0 sc1\n\t"
      "global_load_dwordx4 %3, %11, off sc0 sc1\n\t"
      "global_load_dwordx4 %4, %12, off sc0 sc1\n\t"
      "global_load_dwordx4 %5, %13, off sc0 sc1\n\t"
      "global_load_dwordx4 %6, %14, off sc0 sc1\n\t"
      "global_load_dwordx4 %7, %15, off sc0 sc1\n\t"
      "s_waitcnt vmcnt(0)"
      : "=&v"(t0), "=&v"(t1), "=&v"(t2), "=&v"(t3),
        "=&v"(t4), "=&v"(t5), "=&v"(t6), "=&v"(t7)
      : "v"(pa0), "v"(pa1), "v"(pa2), "v"(pa3),
        "v"(pb0), "v"(pb1), "v"(pb2), "v"(pb3)
      : "memory");
  *(i32x4*)(ldsA + (r0 + 0) * LROW + lane * 8) = t0;
  *(i32x4*)(ldsA + (r0 + 1) * LROW + lane * 8) = t1;
  *(i32x4*)(ldsA + (r0 + 2) * LROW + lane * 8) = t2;
  *(i32x4*)(ldsA + (r0 + 3) * LROW + lane * 8) = t3;
  *(i32x4*)(ldsB + (r0 + 0) * LROW + lane * 8) = t4;
  *(i32x4*)(ldsB + (r0 + 1) * LROW + lane * 8) = t5;
  *(i32x4*)(ldsB + (r0 + 2) * LROW + lane * 8) = t6;
  *(i32x4*)(ldsB + (r0 + 3) * LROW + lane * 8) = t7;
}

// MFMA A-fragment from staged LDS: single b128 (16-B aligned by LROW=520).
__device__ __forceinline__ short8 frag_read(const short* __restrict__ lds,
                                            int lane, int ks) {
  return *(const short8*)(lds + (lane & 15) * LROW + (lane >> 4) * 8 + ks * 32);
}

__global__ void out_init(float* out, const float* bout) {
  int i = blockIdx.x * 256 + threadIdx.x;
  if (i < Bsz * Tlen) out[i] = bout[0];
}

// ---- weight pack: unchanged from R6-R15 (verified correct) ----
__global__ void pack_kernel(const float* __restrict__ Whh0,
                            const float* __restrict__ Wih1, const float* __restrict__ Whh1,
                            const float* __restrict__ Wih2, const float* __restrict__ Whh2,
                            short* __restrict__ Bpack) {
  int ch = blockIdx.x * 256 + threadIdx.x;
  const int L0C = 64 * 16 * 2 * 64;
  const int L12C = 64 * 32 * 2 * 64;
  if (ch >= L0C + 2 * L12C) return;
  int layer, rel, KS;
  const float* Wih;
  const float* Whh;
  if (ch < L0C) { layer = 0; rel = ch; KS = 16; Wih = nullptr; Whh = Whh0; }
  else if (ch < L0C + L12C) { layer = 1; rel = ch - L0C; KS = 32; Wih = Wih1; Whh = Whh1; }
  else { layer = 2; rel = ch - L0C - L12C; KS = 32; Wih = Wih2; Whh = Whh2; }
  int lane = rel & 63;
  int nt = (rel >> 6) & 1;
  int rest = rel >> 7;          // (d*4+w)*KS + ks
  int ks = rest % KS;
  int dw = rest / KS;
  int w = dw & 3;
  int d = dw >> 2;
  int col = nt * 16 + (lane & 15);
  int row = (col >> 3) * Hdim + d * 32 + w * 8 + (col & 7);
  int kbase = ks * 32 + (lane >> 4) * 8;
  short8 v;
#pragma unroll
  for (int e = 0; e < 8; ++e) {
    int k = kbase + e;
    float wt;
    if (layer == 0) wt = Whh[row * Hdim + k];
    else wt = (k < Hdim) ? Wih[row * Hdim + k] : Whh[row * Hdim + (k - Hdim)];
    v[e] = f2bf(wt);
  }
  ((short8*)Bpack)[ch] = v;
}

__global__ __launch_bounds__(256, 1)
void lstm_persist(const float* __restrict__ x,
                  const float* __restrict__ Wih0v,
                  const float* __restrict__ bih0, const float* __restrict__ bhh0,
                  const float* __restrict__ bih1, const float* __restrict__ bhh1,
                  const float* __restrict__ bih2, const float* __restrict__ bhh2,
                  const float* __restrict__ Wout,
                  const short* __restrict__ Bpack,
                  short* __restrict__ rings,
                  uint32_t* __restrict__ flags,
                  float* __restrict__ out) {
  const int blk = blockIdx.x;
  const int layer = blk >> 6;          // 0..2
  const int g = (blk >> 4) & 3;        // batch group (16 rows)
  const int d = blk & 15;              // dim-block (32 h-dims)
  const int tid = threadIdx.x;
  const int lane = tid & 63;
  const int wave = tid >> 6;           // 0..3 = N-slice; role split at publish/poll

  __shared__ short ldsA[16 * LROW];    // staged prev-layer h
  __shared__ short ldsB[16 * LROW];    // staged own-layer h
  __shared__ short hbuf[16][32];       // [group-row][dim within block]
  __shared__ float pbuf[4][16];        // out-head partials [wave][group-row]

  // ---- persistent B fragments: plain loads + keepalive pin (R4-R11-proven) ----
  short8 bw[32][2];
  {
    const short8* bp = (const short8*)Bpack;
    if (layer == 0) {
#pragma unroll
      for (int ks = 0; ks < 16; ++ks) {
        bw[ks][0] = bp[((((d * 4 + wave) * 16 + ks) * 2 + 0) * 64) + lane];
        bw[ks][1] = bp[((((d * 4 + wave) * 16 + ks) * 2 + 1) * 64) + lane];
        asm volatile("" : "+v"(bw[ks][0]), "+v"(bw[ks][1]));
      }
    } else {
      const int base = (layer == 1) ? 131072 : 393216;
#pragma unroll
      for (int ks = 0; ks < 32; ++ks) {
        bw[ks][0] = bp[base + (((d * 4 + wave) * 32 + ks) * 2 + 0) * 64 + lane];
        bw[ks][1] = bp[base + (((d * 4 + wave) * 32 + ks) * 2 + 1) * 64 + lane];
        asm volatile("" : "+v"(bw[ks][0]), "+v"(bw[ks][1]));
      }
    }
  }

  const float* bih = (layer == 0) ? bih0 : (layer == 1 ? bih1 : bih2);
  const float* bhh = (layer == 0) ? bhh0 : (layer == 1 ? bhh1 : bhh2);
  const int dimb = d * 32 + wave * 8 + (lane & 7);
  const int row0 = (((lane & 15) >> 3)) * Hdim + dimb;       // gates i/f
  const int row1 = (((lane & 15) >> 3) + 2) * Hdim + dimb;   // gates g/o
  const float bias0 = bih[row0] + bhh[row0];
  const float bias1 = bih[row1] + bhh[row1];
  float xw0 = 0.f, xw1 = 0.f, woutd = 0.f;
  if (layer == 0) { xw0 = Wih0v[row0]; xw1 = Wih0v[row1]; }
  if (layer == 2) woutd = Wout[dimb];

  uint32_t* flagsO = flags + ((layer * 4 + g) * 16) * FSTR;
  const uint32_t* flagsP = flags + (((layer - 1) * 4 + g) * 16) * FSTR;  // guarded layer>0
  const uint32_t* flagsN = flags + (((layer + 1) * 4 + g) * 16) * FSTR;  // guarded layer<2
  short* ringLG = rings + (layer * 4 + g) * GR;
  const short* ringPG = rings + ((layer - 1) * 4 + g) * GR;

  // wave-1 poll lanes: 0-15 own (tgt t), 16-31 prev (tgt t+1, layer>0),
  // 32-47 next-layer backpressure (tgt t+1-RING, layer<2), rest trivial.
  const uint32_t* pptr;
  int pmode;  // 0=own, 1=prev, 2=bp, 3=trivial
  if (lane < 16) { pptr = flagsO + lane * FSTR; pmode = 0; }
  else if (lane < 32 && layer > 0) { pptr = flagsP + (lane - 16) * FSTR; pmode = 1; }
  else if (lane >= 32 && lane < 48 && layer < 2) { pptr = flagsN + (lane - 32) * FSTR; pmode = 2; }
  else { pptr = flagsO; pmode = 3; }

  const int bR = 4 * (lane >> 4);      // group-row base for acc rows

  float c[4] = {0.f, 0.f, 0.f, 0.f};

  for (int t = 0; t < Tlen; ++t) {
    // ---- poll (wave 1) — overlaps wave 0's publish of step t-1 ----
    if (wave == 1) {
      uint32_t tgt;
      if (pmode == 0) tgt = (uint32_t)t;
      else if (pmode == 1) tgt = (uint32_t)(t + 1);
      else if (pmode == 2) tgt = (t + 1 >= RING) ? (uint32_t)(t + 1 - RING) : 0u;
      else tgt = 0u;
      wait_multi(pptr, tgt);
    }
    __syncthreads();  // bar1: poll passed AND wave 0's prior publish ack'd

    // ---- coalesced staging burst (both slots; dummies when absent) ----
    {
      const short* srcA = (layer > 0) ? ringPG + (t & (RING - 1)) * (16 * Hdim) : ringLG;
      const short* srcB = (t > 0) ? ringLG + ((t - 1) & (RING - 1)) * (16 * Hdim) : srcA;
      stage_both(srcA, srcB, ldsA, ldsB, wave, lane);
    }
    __syncthreads();  // bar2: staging complete

    // ---- MFMA ----
    f32x4 acc0 = {bias0, bias0, bias0, bias0};
    f32x4 acc1 = {bias1, bias1, bias1, bias1};
    if (layer > 0) {
#pragma unroll
      for (int ks = 0; ks < 16; ++ks) {
        short8 a = frag_read(ldsA, lane, ks);
        acc0 = mfma16(a, bw[ks][0], acc0);
        acc1 = mfma16(a, bw[ks][1], acc1);
      }
    } else if (t > 0) {
#pragma unroll
      for (int r = 0; r < 4; ++r) {
        float xv = x[(g * 16 + bR + r) * Tlen + (t - 1)];  // DELAY=1
        acc0[r] += xw0 * xv;
        acc1[r] += xw1 * xv;
      }
    }
    if (t > 0) {
      if (layer == 0) {
#pragma unroll
        for (int ks = 0; ks < 16; ++ks) {
          short8 a = frag_read(ldsB, lane, ks);
          acc0 = mfma16(a, bw[ks][0], acc0);
          acc1 = mfma16(a, bw[ks][1], acc1);
        }
      } else {
#pragma unroll
        for (int ks = 0; ks < 16; ++ks) {
          short8 a = frag_read(ldsB, lane, ks);
          acc0 = mfma16(a, bw[16 + ks][0], acc0);
          acc1 = mfma16(a, bw[16 + ks][1], acc1);
        }
      }
    }

    // ---- activations / state update ----
    float parts[4];
#pragma unroll
    for (int r = 0; r < 4; ++r) {
      float a0 = acc0[r], a1 = acc1[r];
      float p0 = __shfl_xor(a0, 8);
      float p1 = __shfl_xor(a1, 8);
      float iv = 1.f / (1.f + __expf(-a0));
      float fv = 1.f / (1.f + __expf(-p0));
      float gv = tanhf(a1);
      float ov = 1.f / (1.f + __expf(-p1));
      c[r] = fv * c[r] + iv * gv;
      float hv = ov * tanhf(c[r]);
      if ((lane & 8) == 0) hbuf[bR + r][wave * 8 + (lane & 7)] = f2bf(hv);
      parts[r] = hv * woutd;
    }
    if (layer == 2) {
#pragma unroll
      for (int r = 0; r < 4; ++r) {
        parts[r] += __shfl_xor(parts[r], 1);
        parts[r] += __shfl_xor(parts[r], 2);
        parts[r] += __shfl_xor(parts[r], 4);
        if ((lane & 15) == 0) pbuf[wave][bR + r] = parts[r];
      }
    }

    __syncthreads();  // bar3: hbuf (+ pbuf) complete

    // ---- publish (wave 0 only): 1 dwordx4 sc0 sc1 per lane + in-asm ack ----
    if (wave == 0) {
      short* hout = ringLG + (t & (RING - 1)) * (16 * Hdim);
      int row = lane >> 2, q = lane & 3;
      i32x4 v = *(const i32x4*)&hbuf[row][q * 8];
      short* dst = hout + row * Hdim + d * 32 + q * 8;
      asm volatile("global_store_dwordx4 %0, %1, off sc0 sc1\n\t"
                   "s_waitcnt vmcnt(0)"
                   :: "v"(dst), "v"(v) : "memory");
      if (lane == 0)
        __hip_atomic_store(flagsO + d * FSTR, (uint32_t)(t + 1), __ATOMIC_RELAXED,
                           __HIP_MEMORY_SCOPE_AGENT);
    }
    // out-head fully off critical path (wave 2; pbuf stable until next act)
    if (layer == 2 && wave == 2 && lane < 16) {
      float s = pbuf[0][lane] + pbuf[1][lane] + pbuf[2][lane] + pbuf[3][lane];
      atomicAdd(out + (g * 16 + lane) * Tlen + t, s);
    }
  }
}

extern "C" void kernel_launch(void* const* d_in, const int* in_sizes, int n_in,
                              void* d_out, int out_size, void* d_ws, size_t ws_size,
                              hipStream_t stream) {
  const float* x    = (const float*)d_in[0];
  const float* Wih0 = (const float*)d_in[1];
  const float* Whh0 = (const float*)d_in[2];
  const float* bih0 = (const float*)d_in[3];
  const float* bhh0 = (const float*)d_in[4];
  const float* Wih1 = (const float*)d_in[5];
  const float* Whh1 = (const float*)d_in[6];
  const float* bih1 = (const float*)d_in[7];
  const float* bhh1 = (const float*)d_in[8];
  const float* Wih2 = (const float*)d_in[9];
  const float* Whh2 = (const float*)d_in[10];
  const float* bih2 = (const float*)d_in[11];
  const float* bhh2 = (const float*)d_in[12];
  const float* Wout = (const float*)d_in[13];
  const float* bout = (const float*)d_in[14];

  char* ws = (char*)d_ws;
  short* Bpack    = (short*)ws;                          // 10,485,760 B
  short* rings    = (short*)(ws + 10485760);             // 1,572,864 B
  uint32_t* flags = (uint32_t*)(ws + 12058624);          // 12,288 B (total ~12.07 MB, proven)
  float* out      = (float*)d_out;

  (void)hipMemsetAsync(flags, 0, 12 * 16 * FSTR * sizeof(uint32_t), stream);
  out_init<<<(Bsz * Tlen + 255) / 256, 256, 0, stream>>>(out, bout);
  pack_kernel<<<2560, 256, 0, stream>>>(Whh0, Wih1, Whh1, Wih2, Whh2, Bpack);
  lstm_persist<<<192, 256, 0, stream>>>(x, Wih0, bih0, bhh0, bih1, bhh1, bih2, bhh2,
                                        Wout, Bpack, rings, flags, out);
}